// Round 1
// baseline (4761.198 us; speedup 1.0000x reference)
//
#include <hip/hip_runtime.h>
#include <hip/hip_bf16.h>

// krignn2: out = C_qk @ inv(C_kk) @ (VALUE*mlp_v(VALUE))
// with C_kk = exp(-cdist(Ks,Ks)) + 1e-3 I,  Ks = KEY*mlp(KEY), Qs = QUERY*mlp(QUERY).
// Strategy: solve C_kk X = Vs (8 RHS) via blocked fp32 Cholesky (LDL in LDS for the
// diagonal blocks), then fuse C_qk into the final contraction (never materialized).

#define NKB 1024
#define BATCH 16

__device__ __forceinline__ int row_of(int e) {
    int i = (int)((sqrtf(8.0f * (float)e + 1.0f) - 1.0f) * 0.5f);
    while ((i + 1) * (i + 2) / 2 <= e) i++;
    while (i * (i + 1) / 2 > e) i--;
    return i;
}

// ---------------- transpose W2 / Wv2 (for coalesced layer-2 reads) -------------
__global__ void k_transpose(const float* __restrict__ W2, const float* __restrict__ Wv2,
                            float* __restrict__ W2T, float* __restrict__ Wv2T) {
    int tid = blockIdx.x * 256 + threadIdx.x;   // 0..32767
    int e = tid & 16383;
    int r = e >> 7, c = e & 127;
    if (tid < 16384) W2T[c * 128 + r] = W2[e];
    else             Wv2T[c * 128 + r] = Wv2[e];
}

// ---------------- MLP (Linear->ReLU->Linear->ReLU->Linear) + elementwise scale --
// thread t = hidden unit t (128 threads). P points per workgroup. DI == DO.
template<int DI, int P>
__global__ void k_mlp(const float* __restrict__ in, const float* __restrict__ W1,
                      const float* __restrict__ b1, const float* __restrict__ W2T,
                      const float* __restrict__ b2, const float* __restrict__ W3,
                      const float* __restrict__ b3, float* __restrict__ out) {
    __shared__ float xs[P][DI];
    __shared__ float h1[P][128];
    __shared__ float h2[P][129];
    int t = threadIdx.x;
    int base = blockIdx.x * P;
    for (int i = t; i < P * DI; i += 128) xs[i / DI][i % DI] = in[base * DI + i];
    __syncthreads();
    float w1r[DI];
#pragma unroll
    for (int d = 0; d < DI; d++) w1r[d] = W1[t * DI + d];
    float b1t = b1[t], b2t = b2[t];
#pragma unroll
    for (int p = 0; p < P; p++) {
        float s = b1t;
#pragma unroll
        for (int d = 0; d < DI; d++) s += w1r[d] * xs[p][d];
        h1[p][t] = fmaxf(s, 0.0f);
    }
    __syncthreads();
    float acc[P];
#pragma unroll
    for (int p = 0; p < P; p++) acc[p] = b2t;
    for (int k = 0; k < 128; k++) {
        float w = W2T[k * 128 + t];
#pragma unroll
        for (int p = 0; p < P; p++) acc[p] += w * h1[p][k];
    }
#pragma unroll
    for (int p = 0; p < P; p++) h2[p][t] = fmaxf(acc[p], 0.0f);
    __syncthreads();
    if (t < P * DI) {
        int p = t / DI, d = t % DI;
        float s = b3[d];
        for (int k = 0; k < 128; k++) s += W3[d * 128 + k] * h2[p][k];
        int gi = base * DI + t;     // == (base+p)*DI + d
        out[gi] = in[gi] * s;       // elementwise scale by MLP output
    }
}

// ---------------- build C_kk = exp(-dist) + nugget*I ---------------------------
__global__ void k_buildC(const float* __restrict__ Ks, float* __restrict__ C) {
    long idx = (long)blockIdx.x * 256 + threadIdx.x;  // 16M elements
    int b = (int)(idx >> 20);
    int rem = (int)(idx & 1048575);
    int i = rem >> 10, j = rem & 1023;
    const float* a = Ks + ((long)b * 1024 + i) * 3;
    const float* bb = Ks + ((long)b * 1024 + j) * 3;
    float d0 = a[0] - bb[0], d1 = a[1] - bb[1], d2 = a[2] - bb[2];
    float dist = sqrtf(d0 * d0 + d1 * d1 + d2 * d2 + 1e-12f);
    float v = __expf(-dist);
    if (i == j) v += 1e-3f;
    C[idx] = v;
}

// ---------------- diagonal-block Cholesky via LDL in packed LDS ----------------
// grid 16 (batch), block 256. Factors A[o:o+128,o:o+128]; writes L back + invdiag.
__global__ void k_potf(float* __restrict__ C, float* __restrict__ invdiag, int o) {
    int b = blockIdx.x, tid = threadIdx.x;
    float* A = C + (long)b * 1048576;
    __shared__ float Lp[8256];  // packed lower 128x128
    for (int e = tid; e < 8256; e += 256) {
        int i = row_of(e); int j = e - i * (i + 1) / 2;
        Lp[e] = A[(long)(o + i) * 1024 + o + j];
    }
    __syncthreads();
    for (int j = 0; j < 128; j++) {
        float dj = Lp[j * (j + 1) / 2 + j];  // pivot (broadcast)
        float inv_dj = 1.0f / dj;
        int trows = 127 - j;
        int count = trows * (trows + 1) / 2;
        for (int e = tid; e < count; e += 256) {
            int rp = row_of(e); int cp = e - rp * (rp + 1) / 2;
            int r = j + 1 + rp, c = j + 1 + cp;
            Lp[r * (r + 1) / 2 + c] -= Lp[r * (r + 1) / 2 + j] * Lp[c * (c + 1) / 2 + j] * inv_dj;
        }
        __syncthreads();
    }
    // convert LDL -> Cholesky: Lc[i][j] = raw[i][j]*rsqrt(d_j); diag = sqrt(d_j)
    for (int e = tid; e < 8256; e += 256) {
        int i = row_of(e); int j = e - i * (i + 1) / 2;
        float dj = Lp[j * (j + 1) / 2 + j];
        float rs = rsqrtf(dj);
        float v = (i == j) ? sqrtf(dj) : Lp[e] * rs;
        A[(long)(o + i) * 1024 + o + j] = v;
        if (i == j) invdiag[b * 1024 + o + j] = rs;
    }
}

// ---------------- panel TRSM: L21 = A21 * L11^{-T} (row substitution) ----------
// grid (m/64, 16), block 64. Rows held in LDS, JB=8 blocked substitution.
__global__ void k_trsm(float* __restrict__ C, const float* __restrict__ invdiag, int o) {
    int b = blockIdx.y, t = threadIdx.x;
    float* A = C + (long)b * 1048576;
    const float* invd = invdiag + b * 1024 + o;
    int row0 = o + 128 + blockIdx.x * 64;
    __shared__ float rows[64][129];
    for (int e = t; e < 64 * 128; e += 64) {
        int r = e >> 7, c = e & 127;
        rows[r][c] = A[(long)(row0 + r) * 1024 + o + c];
    }
    __syncthreads();
    const float* L11 = A + (long)o * 1024 + o;  // stride 1024
    float vals[8];
    for (int jb = 0; jb < 128; jb += 8) {
#pragma unroll
        for (int q = 0; q < 8; q++) {
            int j = jb + q;
            float s = rows[t][j];
#pragma unroll
            for (int p = 0; p < 8; p++) {
                if (p < q) s -= L11[(long)j * 1024 + jb + p] * vals[p];
            }
            vals[q] = s * invd[j];
            rows[t][j] = vals[q];
        }
        for (int k = jb + 8; k < 128; k++) {
            float s = rows[t][k];
            const float* lrow = L11 + (long)k * 1024 + jb;
#pragma unroll
            for (int q = 0; q < 8; q++) s -= lrow[q] * vals[q];
            rows[t][k] = s;
        }
    }
    __syncthreads();
    for (int e = t; e < 64 * 128; e += 64) {
        int r = e >> 7, c = e & 127;
        A[(long)(row0 + r) * 1024 + o + c] = rows[r][c];
    }
}

// ---------------- SYRK: A22(lower) -= L21 @ L21^T ------------------------------
// grid (npairs, 16), block 256. 64x64 tiles, 4x4 per thread, K=128 in 2 chunks.
__global__ void k_syrk(float* __restrict__ C, int o) {
    int b = blockIdx.y;
    float* A = C + (long)b * 1048576;
    int row0 = o + 128;
    int pair = blockIdx.x;
    int ti = row_of(pair);
    int tj = pair - ti * (ti + 1) / 2;
    int bi = row0 + ti * 64, bj = row0 + tj * 64;
    __shared__ __align__(16) float Asub[64][68];  // k-major [k][r]
    __shared__ __align__(16) float Bsub[64][68];
    int tid = threadIdx.x;
    int tx = tid & 15, ty = tid >> 4;
    float acc[4][4] = {};
    for (int kc = 0; kc < 128; kc += 64) {
        for (int e = tid; e < 64 * 64; e += 256) {
            int r = e >> 6, k = e & 63;
            Asub[k][r] = A[(long)(bi + r) * 1024 + o + kc + k];
        }
        for (int e = tid; e < 64 * 64; e += 256) {
            int r = e >> 6, k = e & 63;
            Bsub[k][r] = A[(long)(bj + r) * 1024 + o + kc + k];
        }
        __syncthreads();
#pragma unroll 4
        for (int k = 0; k < 64; k++) {
            float4 av = *(const float4*)&Asub[k][ty * 4];
            float4 bv = *(const float4*)&Bsub[k][tx * 4];
            float aa[4] = {av.x, av.y, av.z, av.w};
            float bb4[4] = {bv.x, bv.y, bv.z, bv.w};
#pragma unroll
            for (int i = 0; i < 4; i++)
#pragma unroll
                for (int j = 0; j < 4; j++) acc[i][j] += aa[i] * bb4[j];
        }
        __syncthreads();
    }
#pragma unroll
    for (int i = 0; i < 4; i++) {
        long rbase = (long)(bi + ty * 4 + i) * 1024 + bj + tx * 4;
#pragma unroll
        for (int j = 0; j < 4; j++) A[rbase + j] -= acc[i][j];
    }
}

// ---------------- triangular solves: X = L^{-T} L^{-1} Vs (8 RHS) --------------
// grid 16 (batch), block 1024 (thread = row). Wave-shfl 64-blocks.
__global__ void k_solve(const float* __restrict__ C, const float* __restrict__ invdiag,
                        float* __restrict__ V) {
    int b = blockIdx.x, tid = threadIdx.x;
    const float* L = C + (long)b * 1048576;
    const float* invd = invdiag + b * 1024;
    __shared__ float ybuf[64][8];
    float acc[8];
    {
        const float* vp = V + ((long)b * 1024 + tid) * 8;
#pragma unroll
        for (int c = 0; c < 8; c++) acc[c] = vp[c];
    }
    int lane = tid & 63, wave = tid >> 6;
    // forward: y = L^{-1} v
    for (int blk = 0; blk < 16; blk++) {
        int base = blk * 64;
        if (wave == blk) {
            for (int i = 0; i < 64; i++) {
                int gi = base + i;
                float di = invd[gi];
                float yi[8];
#pragma unroll
                for (int c = 0; c < 8; c++) yi[c] = __shfl(acc[c], i) * di;
                if (lane == i) {
#pragma unroll
                    for (int c = 0; c < 8; c++) acc[c] = yi[c];
                } else if (lane > i) {
                    float lv = L[(long)(base + lane) * 1024 + gi];
#pragma unroll
                    for (int c = 0; c < 8; c++) acc[c] -= lv * yi[c];
                }
            }
#pragma unroll
            for (int c = 0; c < 8; c++) ybuf[lane][c] = acc[c];
        }
        __syncthreads();
        if (tid > base + 63) {
            const float* lrow = L + (long)tid * 1024 + base;
            for (int i = 0; i < 64; i++) {
                float lv = lrow[i];
#pragma unroll
                for (int c = 0; c < 8; c++) acc[c] -= lv * ybuf[i][c];
            }
        }
        __syncthreads();
    }
    // backward: x = L^{-T} y
    for (int blk = 15; blk >= 0; blk--) {
        int base = blk * 64;
        if (wave == blk) {
            for (int i = 63; i >= 0; i--) {
                int gi = base + i;
                float di = invd[gi];
                float xi[8];
#pragma unroll
                for (int c = 0; c < 8; c++) xi[c] = __shfl(acc[c], i) * di;
                if (lane == i) {
#pragma unroll
                    for (int c = 0; c < 8; c++) acc[c] = xi[c];
                } else if (lane < i) {
                    float lv = L[(long)gi * 1024 + base + lane];
#pragma unroll
                    for (int c = 0; c < 8; c++) acc[c] -= lv * xi[c];
                }
            }
#pragma unroll
            for (int c = 0; c < 8; c++) ybuf[lane][c] = acc[c];
        }
        __syncthreads();
        if (tid < base) {
            for (int i = 0; i < 64; i++) {
                float lv = L[(long)(base + i) * 1024 + tid];  // coalesced across lanes
#pragma unroll
                for (int c = 0; c < 8; c++) acc[c] -= lv * ybuf[i][c];
            }
        }
        __syncthreads();
    }
    float* xp = V + ((long)b * 1024 + tid) * 8;
#pragma unroll
    for (int c = 0; c < 8; c++) xp[c] = acc[c];
}

// ---------------- fused output: out[q,:] = sum_k exp(-d(Qs_q,Ks_k)) X[k,:] -----
__global__ void k_out(const float* __restrict__ Qs, const float* __restrict__ Ks,
                      const float* __restrict__ X, float* __restrict__ out) {
    int g = blockIdx.x * 64 + threadIdx.x;  // 0..16383
    int b = g >> 10;
    const float* qp = Qs + (long)g * 3;
    float qx = qp[0], qy = qp[1], qz = qp[2];
    const float* kp = Ks + (long)b * 1024 * 3;
    const float* xp = X + (long)b * 1024 * 8;
    float acc[8] = {};
    for (int k = 0; k < 1024; k++) {
        float dx = qx - kp[k * 3 + 0];
        float dy = qy - kp[k * 3 + 1];
        float dz = qz - kp[k * 3 + 2];
        float w = __expf(-sqrtf(dx * dx + dy * dy + dz * dz + 1e-12f));
#pragma unroll
        for (int c = 0; c < 8; c++) acc[c] += w * xp[k * 8 + c];
    }
    float* op = out + (long)g * 8;
#pragma unroll
    for (int c = 0; c < 8; c++) op[c] = acc[c];
}

extern "C" void kernel_launch(void* const* d_in, const int* in_sizes, int n_in,
                              void* d_out, int out_size, void* d_ws, size_t ws_size,
                              hipStream_t stream) {
    const float* KEY   = (const float*)d_in[0];
    const float* VALUE = (const float*)d_in[1];
    const float* QUERY = (const float*)d_in[2];
    const float* W1w = (const float*)d_in[3];  const float* W1b = (const float*)d_in[4];
    const float* W2w = (const float*)d_in[5];  const float* W2b = (const float*)d_in[6];
    const float* W3w = (const float*)d_in[7];  const float* W3b = (const float*)d_in[8];
    const float* Wv1w = (const float*)d_in[9]; const float* Wv1b = (const float*)d_in[10];
    const float* Wv2w = (const float*)d_in[11];const float* Wv2b = (const float*)d_in[12];
    const float* Wv3w = (const float*)d_in[13];const float* Wv3b = (const float*)d_in[14];

    float* ws  = (float*)d_ws;
    float* C    = ws;                 // 16*1024*1024
    float* Ks   = C + 16777216;       // 16*1024*3
    float* Qs   = Ks + 49152;
    float* Vs   = Qs + 49152;         // 16*1024*8 (becomes X in place)
    float* W2T  = Vs + 131072;
    float* Wv2T = W2T + 16384;
    float* invd = Wv2T + 16384;       // 16*1024

    float* out = (float*)d_out;

    hipLaunchKernelGGL(k_transpose, dim3(128), dim3(256), 0, stream, W2w, Wv2w, W2T, Wv2T);
    hipLaunchKernelGGL((k_mlp<3, 32>), dim3(512), dim3(128), 0, stream,
                       KEY, W1w, W1b, W2T, W2b, W3w, W3b, Ks);
    hipLaunchKernelGGL((k_mlp<3, 32>), dim3(512), dim3(128), 0, stream,
                       QUERY, W1w, W1b, W2T, W2b, W3w, W3b, Qs);
    hipLaunchKernelGGL((k_mlp<8, 16>), dim3(1024), dim3(128), 0, stream,
                       VALUE, Wv1w, Wv1b, Wv2T, Wv2b, Wv3w, Wv3b, Vs);
    hipLaunchKernelGGL(k_buildC, dim3(65536), dim3(256), 0, stream, Ks, C);

    for (int s = 0; s < 8; s++) {
        int o = s * 128;
        hipLaunchKernelGGL(k_potf, dim3(16), dim3(256), 0, stream, C, invd, o);
        int m = 1024 - o - 128;
        if (m > 0) {
            hipLaunchKernelGGL(k_trsm, dim3(m / 64, 16), dim3(64), 0, stream, C, invd, o);
            int nt = m / 64;
            int np = nt * (nt + 1) / 2;
            hipLaunchKernelGGL(k_syrk, dim3(np, 16), dim3(256), 0, stream, C, o);
        }
    }
    hipLaunchKernelGGL(k_solve, dim3(16), dim3(1024), 0, stream, C, invd, Vs);
    hipLaunchKernelGGL(k_out, dim3(256), dim3(64), 0, stream, Qs, Ks, Vs, out);
}

// Round 2
// 3336.206 us; speedup vs baseline: 1.4271x; 1.4271x over previous
//
#include <hip/hip_runtime.h>
#include <hip/hip_bf16.h>

// krignn2: out = C_qk @ inv(C_kk) @ (VALUE*mlp_v(VALUE))
// C_kk = exp(-cdist(Ks,Ks)) + 1e-3 I,  Ks = KEY*mlp(KEY), Qs = QUERY*mlp(QUERY).
// Blocked fp32 Cholesky (LDL, rank-8 panels in LDS), fused C_qk contraction.
// R2: coalesced solve via lower->upper mirror; potf without per-step row_of;
//     trsm with LDS-staged L11 panel; k_out LDS-tiled with k-split.

__device__ __forceinline__ int row_of(int e) {
    int i = (int)((sqrtf(8.0f * (float)e + 1.0f) - 1.0f) * 0.5f);
    while ((i + 1) * (i + 2) / 2 <= e) i++;
    while (i * (i + 1) / 2 > e) i--;
    return i;
}

// ---------------- transpose W2 / Wv2 (for coalesced layer-2 reads) -------------
__global__ void k_transpose(const float* __restrict__ W2, const float* __restrict__ Wv2,
                            float* __restrict__ W2T, float* __restrict__ Wv2T) {
    int tid = blockIdx.x * 256 + threadIdx.x;   // 0..32767
    int e = tid & 16383;
    int r = e >> 7, c = e & 127;
    if (tid < 16384) W2T[c * 128 + r] = W2[e];
    else             Wv2T[c * 128 + r] = Wv2[e];
}

// ---------------- MLP (Linear->ReLU->Linear->ReLU->Linear) + elementwise scale --
template<int DI, int P>
__global__ void k_mlp(const float* __restrict__ in, const float* __restrict__ W1,
                      const float* __restrict__ b1, const float* __restrict__ W2T,
                      const float* __restrict__ b2, const float* __restrict__ W3,
                      const float* __restrict__ b3, float* __restrict__ out) {
    __shared__ float xs[P][DI];
    __shared__ float h1[P][128];
    __shared__ float h2[P][129];
    int t = threadIdx.x;
    int base = blockIdx.x * P;
    for (int i = t; i < P * DI; i += 128) xs[i / DI][i % DI] = in[base * DI + i];
    __syncthreads();
    float w1r[DI];
#pragma unroll
    for (int d = 0; d < DI; d++) w1r[d] = W1[t * DI + d];
    float b1t = b1[t], b2t = b2[t];
#pragma unroll
    for (int p = 0; p < P; p++) {
        float s = b1t;
#pragma unroll
        for (int d = 0; d < DI; d++) s += w1r[d] * xs[p][d];
        h1[p][t] = fmaxf(s, 0.0f);
    }
    __syncthreads();
    float acc[P];
#pragma unroll
    for (int p = 0; p < P; p++) acc[p] = b2t;
    for (int k = 0; k < 128; k++) {
        float w = W2T[k * 128 + t];
#pragma unroll
        for (int p = 0; p < P; p++) acc[p] += w * h1[p][k];
    }
#pragma unroll
    for (int p = 0; p < P; p++) h2[p][t] = fmaxf(acc[p], 0.0f);
    __syncthreads();
    if (t < P * DI) {
        int p = t / DI, d = t % DI;
        float s = b3[d];
        for (int k = 0; k < 128; k++) s += W3[d * 128 + k] * h2[p][k];
        int gi = base * DI + t;
        out[gi] = in[gi] * s;
    }
}

// ---------------- build C_kk = exp(-dist) + nugget*I ---------------------------
__global__ void k_buildC(const float* __restrict__ Ks, float* __restrict__ C) {
    long idx = (long)blockIdx.x * 256 + threadIdx.x;  // 16M elements
    int b = (int)(idx >> 20);
    int rem = (int)(idx & 1048575);
    int i = rem >> 10, j = rem & 1023;
    const float* a = Ks + ((long)b * 1024 + i) * 3;
    const float* bb = Ks + ((long)b * 1024 + j) * 3;
    float d0 = a[0] - bb[0], d1 = a[1] - bb[1], d2 = a[2] - bb[2];
    float dist = sqrtf(d0 * d0 + d1 * d1 + d2 * d2 + 1e-12f);
    float v = __expf(-dist);
    if (i == j) v += 1e-3f;
    C[idx] = v;
}

// ---------------- diagonal-block LDL->Cholesky, rank-8 panels in LDS -----------
// grid 16 (batch), block 256. Fixed element ownership, no row_of in hot loop.
__global__ void k_potf(float* __restrict__ C, float* __restrict__ invdiag, int o) {
    int b = blockIdx.x, tid = threadIdx.x;
    float* A = C + (long)b * 1048576;
    __shared__ float Lp[8256];                      // packed lower 128x128
    __shared__ __align__(16) float colv[128][8];    // raw l*d column values
    __shared__ __align__(16) float colw[128][8];    // unit-L column values
    __shared__ float dinv[8];
    // ownership map: slot s -> element e = tid + 256*s, (r,c) computed ONCE
    int rs_[33], cs_[33];
#pragma unroll
    for (int s = 0; s < 33; s++) {
        int e = tid + 256 * s;
        if (e < 8256) { int r = row_of(e); rs_[s] = r; cs_[s] = e - r * (r + 1) / 2; }
        else { rs_[s] = -1; cs_[s] = 0; }
    }
#pragma unroll
    for (int s = 0; s < 33; s++)
        if (rs_[s] >= 0)
            Lp[tid + 256 * s] = A[(long)(o + rs_[s]) * 1024 + o + cs_[s]];
    __syncthreads();

    int r = tid;                       // row owned in panel phase (tid<128)
    int roff = r * (r + 1) / 2;
    for (int jb = 0; jb < 128; jb += 8) {
        float cv[8];
#pragma unroll 1
        for (int q = 0; q < 8; q++) {
            int j = jb + q;
            if (r < 128 && r >= j) {
                float v = Lp[roff + j];
#pragma unroll
                for (int p = 0; p < 8; p++)
                    if (p < q) v -= cv[p] * colw[j][p];   // lazy panel update
                cv[q] = v;
                colv[r][q] = v;
                if (r == j) dinv[q] = 1.0f / v;
            }
            __syncthreads();
            if (r < 128 && r >= j) {
                colw[r][q] = cv[q] * dinv[q];
                Lp[roff + j] = cv[q];                     // finalize raw column
            }
            __syncthreads();
        }
        // trailing rank-8 update for columns c > jb+7
#pragma unroll
        for (int s = 0; s < 33; s++) {
            int rr2 = rs_[s], cc2 = cs_[s];
            if (rr2 >= 0 && cc2 > jb + 7) {
                float4 va = *(const float4*)&colv[rr2][0];
                float4 vb = *(const float4*)&colv[rr2][4];
                float4 wa = *(const float4*)&colw[cc2][0];
                float4 wb = *(const float4*)&colw[cc2][4];
                float acc = Lp[tid + 256 * s];
                acc -= va.x * wa.x + va.y * wa.y + va.z * wa.z + va.w * wa.w
                     + vb.x * wb.x + vb.y * wb.y + vb.z * wb.z + vb.w * wb.w;
                Lp[tid + 256 * s] = acc;
            }
        }
        __syncthreads();
    }
    // LDL -> Cholesky conversion + invdiag
    if (tid < 128)
        invdiag[b * 1024 + o + tid] = rsqrtf(Lp[roff + tid]);
#pragma unroll
    for (int s = 0; s < 33; s++) {
        int rr2 = rs_[s], cc2 = cs_[s];
        if (rr2 >= 0) {
            float dj = Lp[cc2 * (cc2 + 1) / 2 + cc2];
            float v = (rr2 == cc2) ? sqrtf(dj) : Lp[tid + 256 * s] * rsqrtf(dj);
            A[(long)(o + rr2) * 1024 + o + cc2] = v;
        }
    }
}

// ---------------- panel TRSM: L21 = A21 * L11^{-T}, L11 panel staged in LDS ----
// grid (m/64, 16), block 64.
__global__ void k_trsm(float* __restrict__ C, const float* __restrict__ invdiag, int o) {
    int b = blockIdx.y, t = threadIdx.x;
    float* A = C + (long)b * 1048576;
    const float* invd = invdiag + b * 1024 + o;
    int row0 = o + 128 + blockIdx.x * 64;
    __shared__ float rows[64][129];
    __shared__ __align__(16) float Lpan[128][8];
    __shared__ float sinv[128];
    for (int e = t; e < 64 * 128; e += 64) {
        int rr = e >> 7, c = e & 127;
        rows[rr][c] = A[(long)(row0 + rr) * 1024 + o + c];
    }
    for (int i = t; i < 128; i += 64) sinv[i] = invd[i];
    __syncthreads();
    const float* L11 = A + (long)o * 1024 + o;  // stride 1024
    for (int jb = 0; jb < 128; jb += 8) {
        // stage panel columns jb..jb+7, rows jb..127
        for (int e = t; e < (128 - jb) * 8; e += 64) {
            int k = jb + (e >> 3), q = e & 7;
            Lpan[k][q] = L11[(long)k * 1024 + jb + q];
        }
        __syncthreads();
        float vals[8];
#pragma unroll
        for (int q = 0; q < 8; q++) {
            float s = rows[t][jb + q];
#pragma unroll
            for (int p = 0; p < 8; p++)
                if (p < q) s -= Lpan[jb + q][p] * vals[p];   // LDS broadcast
            vals[q] = s * sinv[jb + q];
            rows[t][jb + q] = vals[q];
        }
        for (int k = jb + 8; k < 128; k++) {
            float4 la = *(const float4*)&Lpan[k][0];
            float4 lb = *(const float4*)&Lpan[k][4];
            float s = rows[t][k];
            s -= la.x * vals[0] + la.y * vals[1] + la.z * vals[2] + la.w * vals[3]
               + lb.x * vals[4] + lb.y * vals[5] + lb.z * vals[6] + lb.w * vals[7];
            rows[t][k] = s;
        }
        __syncthreads();
    }
    for (int e = t; e < 64 * 128; e += 64) {
        int rr = e >> 7, c = e & 127;
        A[(long)(row0 + rr) * 1024 + o + c] = rows[rr][c];
    }
}

// ---------------- SYRK: A22(lower) -= L21 @ L21^T ------------------------------
__global__ void k_syrk(float* __restrict__ C, int o) {
    int b = blockIdx.y;
    float* A = C + (long)b * 1048576;
    int row0 = o + 128;
    int pair = blockIdx.x;
    int ti = row_of(pair);
    int tj = pair - ti * (ti + 1) / 2;
    int bi = row0 + ti * 64, bj = row0 + tj * 64;
    __shared__ __align__(16) float Asub[64][68];  // k-major [k][r]
    __shared__ __align__(16) float Bsub[64][68];
    int tid = threadIdx.x;
    int tx = tid & 15, ty = tid >> 4;
    float acc[4][4] = {};
    for (int kc = 0; kc < 128; kc += 64) {
        for (int e = tid; e < 64 * 64; e += 256) {
            int rr = e >> 6, k = e & 63;
            Asub[k][rr] = A[(long)(bi + rr) * 1024 + o + kc + k];
        }
        for (int e = tid; e < 64 * 64; e += 256) {
            int rr = e >> 6, k = e & 63;
            Bsub[k][rr] = A[(long)(bj + rr) * 1024 + o + kc + k];
        }
        __syncthreads();
#pragma unroll 4
        for (int k = 0; k < 64; k++) {
            float4 av = *(const float4*)&Asub[k][ty * 4];
            float4 bv = *(const float4*)&Bsub[k][tx * 4];
            float aa[4] = {av.x, av.y, av.z, av.w};
            float bb4[4] = {bv.x, bv.y, bv.z, bv.w};
#pragma unroll
            for (int i = 0; i < 4; i++)
#pragma unroll
                for (int j = 0; j < 4; j++) acc[i][j] += aa[i] * bb4[j];
        }
        __syncthreads();
    }
#pragma unroll
    for (int i = 0; i < 4; i++) {
        long rbase = (long)(bi + ty * 4 + i) * 1024 + bj + tx * 4;
#pragma unroll
        for (int j = 0; j < 4; j++) A[rbase + j] -= acc[i][j];
    }
}

// ---------------- mirror lower factor into (unused) upper triangle -------------
// grid (528, 16), block 256 (32x8 tiles). Enables coalesced forward solve.
__global__ void k_mirror(float* __restrict__ C) {
    int b = blockIdx.y;
    float* A = C + (long)b * 1048576;
    int pair = blockIdx.x;
    int ti = row_of(pair);
    int tj = pair - ti * (ti + 1) / 2;
    __shared__ float s[32][33];
    int tx = threadIdx.x & 31, ty = threadIdx.x >> 5;
    for (int rr = ty; rr < 32; rr += 8)
        s[rr][tx] = A[(long)(ti * 32 + rr) * 1024 + tj * 32 + tx];
    __syncthreads();
    for (int rr = ty; rr < 32; rr += 8) {
        int gr = tj * 32 + rr, gc = ti * 32 + tx;
        if (gc > gr) A[(long)gr * 1024 + gc] = s[tx][rr];
    }
}

// ---------------- triangular solves: X = L^{-T} L^{-1} Vs (8 RHS) --------------
// grid 16 (batch), block 1024. Forward pass reads mirrored upper (coalesced).
__global__ void k_solve(const float* __restrict__ C, const float* __restrict__ invdiag,
                        float* __restrict__ V) {
    int b = blockIdx.x, tid = threadIdx.x;
    const float* L = C + (long)b * 1048576;
    const float* invd = invdiag + b * 1024;
    __shared__ __align__(16) float ybuf[64][8];
    float acc[8];
    {
        const float* vp = V + ((long)b * 1024 + tid) * 8;
#pragma unroll
        for (int c = 0; c < 8; c++) acc[c] = vp[c];
    }
    int lane = tid & 63, wave = tid >> 6;
    // forward: y = L^{-1} v   (reads L[r][c] as mirrored upper [c][r])
    for (int blk = 0; blk < 16; blk++) {
        int base = blk * 64;
        if (wave == blk) {
            for (int i = 0; i < 64; i++) {
                int gi = base + i;
                float di = invd[gi];
                float yi[8];
#pragma unroll
                for (int c = 0; c < 8; c++) yi[c] = __shfl(acc[c], i) * di;
                if (lane == i) {
#pragma unroll
                    for (int c = 0; c < 8; c++) acc[c] = yi[c];
                } else if (lane > i) {
                    float lv = L[(long)gi * 1024 + base + lane];   // mirrored, coalesced
#pragma unroll
                    for (int c = 0; c < 8; c++) acc[c] -= lv * yi[c];
                }
            }
#pragma unroll
            for (int c = 0; c < 8; c++) ybuf[lane][c] = acc[c];
        }
        __syncthreads();
        if (tid > base + 63) {
            for (int i = 0; i < 64; i++) {
                float lv = L[(long)(base + i) * 1024 + tid];       // mirrored, coalesced
                float4 ya = *(const float4*)&ybuf[i][0];
                float4 yb = *(const float4*)&ybuf[i][4];
                acc[0] -= lv * ya.x; acc[1] -= lv * ya.y;
                acc[2] -= lv * ya.z; acc[3] -= lv * ya.w;
                acc[4] -= lv * yb.x; acc[5] -= lv * yb.y;
                acc[6] -= lv * yb.z; acc[7] -= lv * yb.w;
            }
        }
        __syncthreads();
    }
    // backward: x = L^{-T} y  (reads L lower directly; already coalesced)
    for (int blk = 15; blk >= 0; blk--) {
        int base = blk * 64;
        if (wave == blk) {
            for (int i = 63; i >= 0; i--) {
                int gi = base + i;
                float di = invd[gi];
                float xi[8];
#pragma unroll
                for (int c = 0; c < 8; c++) xi[c] = __shfl(acc[c], i) * di;
                if (lane == i) {
#pragma unroll
                    for (int c = 0; c < 8; c++) acc[c] = xi[c];
                } else if (lane < i) {
                    float lv = L[(long)gi * 1024 + base + lane];
#pragma unroll
                    for (int c = 0; c < 8; c++) acc[c] -= lv * xi[c];
                }
            }
#pragma unroll
            for (int c = 0; c < 8; c++) ybuf[lane][c] = acc[c];
        }
        __syncthreads();
        if (tid < base) {
            for (int i = 0; i < 64; i++) {
                float lv = L[(long)(base + i) * 1024 + tid];
                float4 ya = *(const float4*)&ybuf[i][0];
                float4 yb = *(const float4*)&ybuf[i][4];
                acc[0] -= lv * ya.x; acc[1] -= lv * ya.y;
                acc[2] -= lv * ya.z; acc[3] -= lv * ya.w;
                acc[4] -= lv * yb.x; acc[5] -= lv * yb.y;
                acc[6] -= lv * yb.z; acc[7] -= lv * yb.w;
            }
        }
        __syncthreads();
    }
    float* xp = V + ((long)b * 1024 + tid) * 8;
#pragma unroll
    for (int c = 0; c < 8; c++) xp[c] = acc[c];
}

// ---------------- fused output: out[q,:] = sum_k exp(-d(Qs_q,Ks_k)) X[k,:] -----
// grid 256 (16 batch x 16 query-chunks), block 256 (64 queries x 4 k-subsets).
__global__ void k_out(const float* __restrict__ Qs, const float* __restrict__ Ks,
                      const float* __restrict__ X, float* __restrict__ out) {
    int b = blockIdx.x >> 4;
    int qc = blockIdx.x & 15;
    int t = threadIdx.x;
    int q = t & 63, ks = t >> 6;
    __shared__ float kx[1024][3];                    // 12 KB
    __shared__ __align__(16) float xv[1024][8];      // 32 KB
    __shared__ float red[4][64][8];                  //  8 KB
    for (int i = t; i < 3072; i += 256) kx[i / 3][i % 3] = Ks[b * 3072 + i];
    for (int i = t; i < 8192; i += 256) xv[i >> 3][i & 7] = X[b * 8192 + i];
    __syncthreads();
    int gq = b * 1024 + qc * 64 + q;
    const float* qp = Qs + (long)gq * 3;
    float qx = qp[0], qy = qp[1], qz = qp[2];
    float acc[8] = {};
    int k0 = ks * 256;
#pragma unroll 2
    for (int k = k0; k < k0 + 256; k++) {
        float dx = qx - kx[k][0], dy = qy - kx[k][1], dz = qz - kx[k][2];
        float w = __expf(-sqrtf(dx * dx + dy * dy + dz * dz + 1e-12f));
        float4 xa = *(const float4*)&xv[k][0];
        float4 xb = *(const float4*)&xv[k][4];
        acc[0] += w * xa.x; acc[1] += w * xa.y; acc[2] += w * xa.z; acc[3] += w * xa.w;
        acc[4] += w * xb.x; acc[5] += w * xb.y; acc[6] += w * xb.z; acc[7] += w * xb.w;
    }
#pragma unroll
    for (int c = 0; c < 8; c++) red[ks][q][c] = acc[c];
    __syncthreads();
    if (ks == 0) {
        float* op = out + (long)gq * 8;
#pragma unroll
        for (int c = 0; c < 8; c++)
            op[c] = red[0][q][c] + red[1][q][c] + red[2][q][c] + red[3][q][c];
    }
}

extern "C" void kernel_launch(void* const* d_in, const int* in_sizes, int n_in,
                              void* d_out, int out_size, void* d_ws, size_t ws_size,
                              hipStream_t stream) {
    const float* KEY   = (const float*)d_in[0];
    const float* VALUE = (const float*)d_in[1];
    const float* QUERY = (const float*)d_in[2];
    const float* W1w = (const float*)d_in[3];  const float* W1b = (const float*)d_in[4];
    const float* W2w = (const float*)d_in[5];  const float* W2b = (const float*)d_in[6];
    const float* W3w = (const float*)d_in[7];  const float* W3b = (const float*)d_in[8];
    const float* Wv1w = (const float*)d_in[9]; const float* Wv1b = (const float*)d_in[10];
    const float* Wv2w = (const float*)d_in[11];const float* Wv2b = (const float*)d_in[12];
    const float* Wv3w = (const float*)d_in[13];const float* Wv3b = (const float*)d_in[14];

    float* ws  = (float*)d_ws;
    float* C    = ws;                 // 16*1024*1024
    float* Ks   = C + 16777216;       // 16*1024*3
    float* Qs   = Ks + 49152;
    float* Vs   = Qs + 49152;         // 16*1024*8 (becomes X in place)
    float* W2T  = Vs + 131072;
    float* Wv2T = W2T + 16384;
    float* invd = Wv2T + 16384;       // 16*1024

    float* out = (float*)d_out;

    hipLaunchKernelGGL(k_transpose, dim3(128), dim3(256), 0, stream, W2w, Wv2w, W2T, Wv2T);
    hipLaunchKernelGGL((k_mlp<3, 32>), dim3(512), dim3(128), 0, stream,
                       KEY, W1w, W1b, W2T, W2b, W3w, W3b, Ks);
    hipLaunchKernelGGL((k_mlp<3, 32>), dim3(512), dim3(128), 0, stream,
                       QUERY, W1w, W1b, W2T, W2b, W3w, W3b, Qs);
    hipLaunchKernelGGL((k_mlp<8, 16>), dim3(1024), dim3(128), 0, stream,
                       VALUE, Wv1w, Wv1b, Wv2T, Wv2b, Wv3w, Wv3b, Vs);
    hipLaunchKernelGGL(k_buildC, dim3(65536), dim3(256), 0, stream, Ks, C);

    for (int s = 0; s < 8; s++) {
        int o = s * 128;
        hipLaunchKernelGGL(k_potf, dim3(16), dim3(256), 0, stream, C, invd, o);
        int m = 1024 - o - 128;
        if (m > 0) {
            hipLaunchKernelGGL(k_trsm, dim3(m / 64, 16), dim3(64), 0, stream, C, invd, o);
            int nt = m / 64;
            int np = nt * (nt + 1) / 2;
            hipLaunchKernelGGL(k_syrk, dim3(np, 16), dim3(256), 0, stream, C, o);
        }
    }
    hipLaunchKernelGGL(k_mirror, dim3(528, 16), dim3(256), 0, stream, C);
    hipLaunchKernelGGL(k_solve, dim3(16), dim3(1024), 0, stream, C, invd, Vs);
    hipLaunchKernelGGL(k_out, dim3(256), dim3(256), 0, stream, Qs, Ks, Vs, out);
}

// Round 3
// 2646.520 us; speedup vs baseline: 1.7990x; 1.2606x over previous
//
#include <hip/hip_runtime.h>
#include <hip/hip_bf16.h>

// krignn2: out = C_qk @ inv(C_kk) @ (VALUE*mlp_v(VALUE))
// C_kk = exp(-cdist(Ks,Ks)) + 1e-3 I,  Ks = KEY*mlp(KEY), Qs = QUERY*mlp(QUERY).
// Blocked fp32 Cholesky (LDL panels), solve with 8 RHS, fused C_qk contraction.
// R3: potf = full-square LDS tile + wave0-shfl panel (no scratch arrays);
//     trsm = register-resident rows (no LDS); syrk = 128x128 tiles 8x8/thread;
//     solve = LDS-staged diag tiles + register strip prefetch; mirror dropped.

__device__ __forceinline__ int row_of(int e) {
    int i = (int)((sqrtf(8.0f * (float)e + 1.0f) - 1.0f) * 0.5f);
    while ((i + 1) * (i + 2) / 2 <= e) i++;
    while (i * (i + 1) / 2 > e) i--;
    return i;
}

// ---------------- transpose W2 / Wv2 (for coalesced layer-2 reads) -------------
__global__ void k_transpose(const float* __restrict__ W2, const float* __restrict__ Wv2,
                            float* __restrict__ W2T, float* __restrict__ Wv2T) {
    int tid = blockIdx.x * 256 + threadIdx.x;   // 0..32767
    int e = tid & 16383;
    int r = e >> 7, c = e & 127;
    if (tid < 16384) W2T[c * 128 + r] = W2[e];
    else             Wv2T[c * 128 + r] = Wv2[e];
}

// ---------------- MLP (Linear->ReLU->Linear->ReLU->Linear) + elementwise scale --
template<int DI, int P>
__global__ void k_mlp(const float* __restrict__ in, const float* __restrict__ W1,
                      const float* __restrict__ b1, const float* __restrict__ W2T,
                      const float* __restrict__ b2, const float* __restrict__ W3,
                      const float* __restrict__ b3, float* __restrict__ out) {
    __shared__ float xs[P][DI];
    __shared__ float h1[P][128];
    __shared__ float h2[P][129];
    int t = threadIdx.x;
    int base = blockIdx.x * P;
    for (int i = t; i < P * DI; i += 128) xs[i / DI][i % DI] = in[base * DI + i];
    __syncthreads();
    float w1r[DI];
#pragma unroll
    for (int d = 0; d < DI; d++) w1r[d] = W1[t * DI + d];
    float b1t = b1[t], b2t = b2[t];
#pragma unroll
    for (int p = 0; p < P; p++) {
        float s = b1t;
#pragma unroll
        for (int d = 0; d < DI; d++) s += w1r[d] * xs[p][d];
        h1[p][t] = fmaxf(s, 0.0f);
    }
    __syncthreads();
    float acc[P];
#pragma unroll
    for (int p = 0; p < P; p++) acc[p] = b2t;
    for (int k = 0; k < 128; k++) {
        float w = W2T[k * 128 + t];
#pragma unroll
        for (int p = 0; p < P; p++) acc[p] += w * h1[p][k];
    }
#pragma unroll
    for (int p = 0; p < P; p++) h2[p][t] = fmaxf(acc[p], 0.0f);
    __syncthreads();
    if (t < P * DI) {
        int p = t / DI, d = t % DI;
        float s = b3[d];
        for (int k = 0; k < 128; k++) s += W3[d * 128 + k] * h2[p][k];
        int gi = base * DI + t;
        out[gi] = in[gi] * s;
    }
}

// ---------------- build C_kk = exp(-dist) + nugget*I ---------------------------
__global__ void k_buildC(const float* __restrict__ Ks, float* __restrict__ C) {
    long idx = (long)blockIdx.x * 256 + threadIdx.x;  // 16M elements
    int b = (int)(idx >> 20);
    int rem = (int)(idx & 1048575);
    int i = rem >> 10, j = rem & 1023;
    const float* a = Ks + ((long)b * 1024 + i) * 3;
    const float* bb = Ks + ((long)b * 1024 + j) * 3;
    float d0 = a[0] - bb[0], d1 = a[1] - bb[1], d2 = a[2] - bb[2];
    float dist = sqrtf(d0 * d0 + d1 * d1 + d2 * d2 + 1e-12f);
    float v = __expf(-dist);
    if (i == j) v += 1e-3f;
    C[idx] = v;
}

// ---------------- diagonal-block factorization (LDL), full tile in LDS ---------
// grid 16 (batch), block 256. Wave-0 shfl panel (8 cols), rank-8 trailing update.
// Loads LOWER triangle and mirrors (upper in global is stale after syrk).
__global__ __launch_bounds__(256) void k_potf(float* __restrict__ C,
                                              float* __restrict__ invdiag, int o) {
    int b = blockIdx.x, tid = threadIdx.x;
    float* A = C + (long)b * 1048576;
    __shared__ float T[128][133];
    __shared__ float cv[128][9];
    __shared__ float cw[128][9];
    __shared__ float rsd[128];
    // load lower triangle, mirror into upper (full symmetric square in LDS)
    {
        int r = tid >> 1, c0 = (tid & 1) * 64;
        const float* src = A + (long)(o + r) * 1024 + o + c0;
#pragma unroll
        for (int k = 0; k < 16; k++) {
            int c = c0 + 4 * k;
            if (c <= r) {
                float4 v = *(const float4*)(src + 4 * k);
                float vv[4] = {v.x, v.y, v.z, v.w};
#pragma unroll
                for (int m = 0; m < 4; m++) {
                    if (c + m <= r) { T[r][c + m] = vv[m]; T[c + m][r] = vv[m]; }
                }
            }
        }
    }
    __syncthreads();
    int lane = tid & 63;
    int rg = tid >> 4;          // rows rg*8 .. rg*8+7
    int cg = tid & 15;          // cols cg + 16*j
    for (int jb = 0; jb < 128; jb += 8) {
        if (tid < 64) {
            // wave-0 LDL panel: columns jb..jb+7, 2 rows per lane, lazy updates
            int r1 = lane, r2 = 64 + lane;
            float v1[8], v2[8], w1[8], w2[8];
#pragma unroll
            for (int q = 0; q < 8; q++) {
                int j = jb + q;
                int jl = j & 63;
                bool hi = (j >= 64);
                float a1 = T[r1][j], a2 = T[r2][j];
#pragma unroll
                for (int p = 0; p < 8; p++) {
                    if (p < q) {
                        float wj = __shfl(hi ? w2[p] : w1[p], jl);
                        a1 -= v1[p] * wj;
                        a2 -= v2[p] * wj;
                    }
                }
                v1[q] = a1; v2[q] = a2;
                float dj = __shfl(hi ? a2 : a1, jl);
                float dinv = 1.0f / dj;
                w1[q] = a1 * dinv; w2[q] = a2 * dinv;
                if ((hi ? r2 : r1) == j) invdiag[b * 1024 + o + j] = rsqrtf(dj);
            }
#pragma unroll
            for (int q = 0; q < 8; q++) {
                T[r1][jb + q] = v1[q];  T[r2][jb + q] = v2[q];
                cv[r1][q] = v1[q];      cv[r2][q] = v2[q];
                cw[r1][q] = w1[q];      cw[r2][q] = w2[q];
            }
        }
        __syncthreads();
        if (jb < 120) {
            // trailing: full square (keeps symmetry; upper garbage never output)
            float va[8][8];
#pragma unroll
            for (int i = 0; i < 8; i++)
#pragma unroll
                for (int p = 0; p < 8; p++) va[i][p] = cv[rg * 8 + i][p];
#pragma unroll
            for (int j = 0; j < 8; j++) {
                int c = cg + 16 * j;
                if (c >= jb + 8) {
                    float wb[8];
#pragma unroll
                    for (int p = 0; p < 8; p++) wb[p] = cw[c][p];
#pragma unroll
                    for (int i = 0; i < 8; i++) {
                        int r = rg * 8 + i;
                        float t = T[r][c];
#pragma unroll
                        for (int p = 0; p < 8; p++) t -= va[i][p] * wb[p];
                        T[r][c] = t;
                    }
                }
            }
        }
        __syncthreads();
    }
    if (tid < 128) rsd[tid] = rsqrtf(T[tid][tid]);
    __syncthreads();
    // writeback lower (LDL -> Cholesky): L[r][c] = v*rsqrt(d_c); diag = sqrt(d)
#pragma unroll
    for (int j = 0; j < 8; j++) {
        int c = cg + 16 * j;
#pragma unroll
        for (int i = 0; i < 8; i++) {
            int r = rg * 8 + i;
            if (c < r)       A[(long)(o + r) * 1024 + o + c] = T[r][c] * rsd[c];
            else if (c == r) A[(long)(o + r) * 1024 + o + c] = sqrtf(T[r][r]);
        }
    }
}

// ---------------- panel TRSM: L21 = A21 * L11^{-T}, rows in registers ----------
// grid (m/64, 16), block 64. Uniform (scalar-friendly) L11 reads, no LDS.
__global__ __launch_bounds__(64) void k_trsm(float* __restrict__ C,
                                             const float* __restrict__ invdiag, int o) {
    int b = blockIdx.y, t = threadIdx.x;
    float* A = C + (long)b * 1048576;
    const float* __restrict__ invd = invdiag + b * 1024 + o;
    const float* __restrict__ L11 = C + (long)b * 1048576 + (long)o * 1024 + o;
    int row = o + 128 + blockIdx.x * 64 + t;
    float* arow = A + (long)row * 1024 + o;
    float r_[128];
#pragma unroll
    for (int k = 0; k < 32; k++) {
        float4 v = *(const float4*)(arow + 4 * k);
        r_[4*k] = v.x; r_[4*k+1] = v.y; r_[4*k+2] = v.z; r_[4*k+3] = v.w;
    }
#pragma unroll
    for (int jb = 0; jb < 128; jb += 8) {
        float vals[8];
#pragma unroll
        for (int q = 0; q < 8; q++) {
            float s = r_[jb + q];
#pragma unroll
            for (int p = 0; p < 8; p++)
                if (p < q) s -= L11[(long)(jb + q) * 1024 + jb + p] * vals[p];
            vals[q] = s * invd[jb + q];
            r_[jb + q] = vals[q];
        }
#pragma unroll
        for (int k = jb + 8; k < 128; k++) {
            const float* lr = L11 + (long)k * 1024 + jb;
            float4 la = *(const float4*)lr;
            float4 lb = *(const float4*)(lr + 4);
            r_[k] -= la.x*vals[0] + la.y*vals[1] + la.z*vals[2] + la.w*vals[3]
                   + lb.x*vals[4] + lb.y*vals[5] + lb.z*vals[6] + lb.w*vals[7];
        }
    }
#pragma unroll
    for (int k = 0; k < 32; k++) {
        float4 v = make_float4(r_[4*k], r_[4*k+1], r_[4*k+2], r_[4*k+3]);
        *(float4*)(arow + 4 * k) = v;
    }
}

// ---------------- SYRK: A22(lower) -= L21 @ L21^T, 128x128 tiles ---------------
// grid (npairs, 16), block 256 (16x16 threads, 8x8 acc each), K=128 in kc=32.
__global__ __launch_bounds__(256) void k_syrk(float* __restrict__ C, int o) {
    int b = blockIdx.y;
    float* A = C + (long)b * 1048576;
    int pair = blockIdx.x;
    int ti = row_of(pair);
    int tj = pair - ti * (ti + 1) / 2;
    int bi = o + 128 + ti * 128, bj = o + 128 + tj * 128;
    __shared__ float As[32][132];
    __shared__ float Bs[32][132];
    int tid = threadIdx.x;
    int tx = tid & 15, ty = tid >> 4;
    float acc[8][8] = {};
    int lr = tid >> 1;                 // load row 0..127
    int lk = (tid & 1) * 16;           // k-half
    for (int kc = 0; kc < 128; kc += 32) {
        {
            const float* src = A + (long)(bi + lr) * 1024 + o + kc + lk;
#pragma unroll
            for (int k4 = 0; k4 < 4; k4++) {
                float4 v = *(const float4*)(src + 4 * k4);
                As[lk + 4*k4    ][lr] = v.x;
                As[lk + 4*k4 + 1][lr] = v.y;
                As[lk + 4*k4 + 2][lr] = v.z;
                As[lk + 4*k4 + 3][lr] = v.w;
            }
            if (bi != bj) {
                const float* sb = A + (long)(bj + lr) * 1024 + o + kc + lk;
#pragma unroll
                for (int k4 = 0; k4 < 4; k4++) {
                    float4 v = *(const float4*)(sb + 4 * k4);
                    Bs[lk + 4*k4    ][lr] = v.x;
                    Bs[lk + 4*k4 + 1][lr] = v.y;
                    Bs[lk + 4*k4 + 2][lr] = v.z;
                    Bs[lk + 4*k4 + 3][lr] = v.w;
                }
            }
        }
        __syncthreads();
        {
            const float (*Bp)[132] = (bi == bj) ? As : Bs;
#pragma unroll
            for (int k = 0; k < 32; k++) {
                float4 a0 = *(const float4*)&As[k][ty * 8];
                float4 a1 = *(const float4*)&As[k][ty * 8 + 4];
                float4 b0 = *(const float4*)&Bp[k][tx * 8];
                float4 b1 = *(const float4*)&Bp[k][tx * 8 + 4];
                float aa[8] = {a0.x,a0.y,a0.z,a0.w,a1.x,a1.y,a1.z,a1.w};
                float bb[8] = {b0.x,b0.y,b0.z,b0.w,b1.x,b1.y,b1.z,b1.w};
#pragma unroll
                for (int i = 0; i < 8; i++)
#pragma unroll
                    for (int j = 0; j < 8; j++) acc[i][j] += aa[i] * bb[j];
            }
        }
        __syncthreads();
    }
#pragma unroll
    for (int i = 0; i < 8; i++) {
        int r = bi + ty * 8 + i;
        float* dst = A + (long)r * 1024 + bj + tx * 8;
        if (bi != bj) {
            float4 p0 = *(const float4*)dst;
            float4 p1 = *(const float4*)(dst + 4);
            p0.x -= acc[i][0]; p0.y -= acc[i][1]; p0.z -= acc[i][2]; p0.w -= acc[i][3];
            p1.x -= acc[i][4]; p1.y -= acc[i][5]; p1.z -= acc[i][6]; p1.w -= acc[i][7];
            *(float4*)dst = p0;
            *(float4*)(dst + 4) = p1;
        } else {
#pragma unroll
            for (int j = 0; j < 8; j++) {
                int c = bj + tx * 8 + j;
                if (c <= r) dst[j] -= acc[i][j];
            }
        }
    }
}

// ---------------- triangular solves: X = L^{-T} L^{-1} Vs (8 RHS) --------------
// grid 16 (batch), block 1024. Diag tiles staged in LDS; strips prefetched to
// registers before the barrier so global latency overlaps the serial solve.
__global__ __launch_bounds__(1024) void k_solve(const float* __restrict__ C,
                                                const float* __restrict__ invdiag,
                                                float* __restrict__ V) {
    int b = blockIdx.x, tid = threadIdx.x;
    const float* L = C + (long)b * 1048576;
    const float* invd = invdiag + b * 1024;
    __shared__ float sdiag[64][65];
    __shared__ __align__(16) float ybuf[64][8];
    float acc[8];
    {
        const float* vp = V + ((long)b * 1024 + tid) * 8;
#pragma unroll
        for (int c = 0; c < 8; c++) acc[c] = vp[c];
    }
    int lane = tid & 63, wave = tid >> 6;
    // ---------- forward: y = L^{-1} v ----------
    for (int blk = 0; blk < 16; blk++) {
        int base = blk * 64;
        bool below = (tid >= base + 64);
        float4 pre[16];
        if (below) {
            const float* sp = L + (long)tid * 1024 + base;
#pragma unroll
            for (int k = 0; k < 16; k++) pre[k] = *(const float4*)(sp + 4 * k);
        }
#pragma unroll
        for (int p = 0; p < 4; p++) {
            int e = tid + p * 1024;
            int i = e >> 6, j = e & 63;
            sdiag[i][j] = L[(long)(base + i) * 1024 + base + j];
        }
        float dreg = invd[base + lane];
        __syncthreads();
        if (wave == blk) {
            for (int i = 0; i < 64; i++) {
                float di = __shfl(dreg, i);
                float yi[8];
#pragma unroll
                for (int c = 0; c < 8; c++) yi[c] = __shfl(acc[c], i) * di;
                if (lane == i) {
#pragma unroll
                    for (int c = 0; c < 8; c++) acc[c] = yi[c];
                } else if (lane > i) {
                    float lv = sdiag[lane][i];
#pragma unroll
                    for (int c = 0; c < 8; c++) acc[c] -= lv * yi[c];
                }
            }
#pragma unroll
            for (int c = 0; c < 8; c++) ybuf[lane][c] = acc[c];
        }
        __syncthreads();
        if (below) {
#pragma unroll
            for (int k = 0; k < 16; k++) {
                float lvv[4] = {pre[k].x, pre[k].y, pre[k].z, pre[k].w};
#pragma unroll
                for (int m = 0; m < 4; m++) {
                    float4 ya = *(const float4*)&ybuf[4 * k + m][0];
                    float4 yb = *(const float4*)&ybuf[4 * k + m][4];
                    float l = lvv[m];
                    acc[0] -= l * ya.x; acc[1] -= l * ya.y;
                    acc[2] -= l * ya.z; acc[3] -= l * ya.w;
                    acc[4] -= l * yb.x; acc[5] -= l * yb.y;
                    acc[6] -= l * yb.z; acc[7] -= l * yb.w;
                }
            }
        }
    }
    // ---------- backward: x = L^{-T} y ----------
    for (int blk = 15; blk >= 0; blk--) {
        int base = blk * 64;
        bool above = (tid < base);
        float pre32[64];
        if (above) {
#pragma unroll
            for (int i = 0; i < 64; i++) pre32[i] = L[(long)(base + i) * 1024 + tid];
        }
#pragma unroll
        for (int p = 0; p < 4; p++) {
            int e = tid + p * 1024;
            int i = e >> 6, j = e & 63;
            sdiag[i][j] = L[(long)(base + i) * 1024 + base + j];
        }
        float dreg = invd[base + lane];
        __syncthreads();
        if (wave == blk) {
            for (int i = 63; i >= 0; i--) {
                float di = __shfl(dreg, i);
                float xi[8];
#pragma unroll
                for (int c = 0; c < 8; c++) xi[c] = __shfl(acc[c], i) * di;
                if (lane == i) {
#pragma unroll
                    for (int c = 0; c < 8; c++) acc[c] = xi[c];
                } else if (lane < i) {
                    float lv = sdiag[i][lane];
#pragma unroll
                    for (int c = 0; c < 8; c++) acc[c] -= lv * xi[c];
                }
            }
#pragma unroll
            for (int c = 0; c < 8; c++) ybuf[lane][c] = acc[c];
        }
        __syncthreads();
        if (above) {
#pragma unroll
            for (int i = 0; i < 64; i++) {
                float lv = pre32[i];
                float4 ya = *(const float4*)&ybuf[i][0];
                float4 yb = *(const float4*)&ybuf[i][4];
                acc[0] -= lv * ya.x; acc[1] -= lv * ya.y;
                acc[2] -= lv * ya.z; acc[3] -= lv * ya.w;
                acc[4] -= lv * yb.x; acc[5] -= lv * yb.y;
                acc[6] -= lv * yb.z; acc[7] -= lv * yb.w;
            }
        }
    }
    float* xp = V + ((long)b * 1024 + tid) * 8;
#pragma unroll
    for (int c = 0; c < 8; c++) xp[c] = acc[c];
}

// ---------------- fused output: out[q,:] = sum_k exp(-d(Qs_q,Ks_k)) X[k,:] -----
// grid 256 (16 batch x 16 query-chunks), block 256 (64 queries x 4 k-subsets).
__global__ void k_out(const float* __restrict__ Qs, const float* __restrict__ Ks,
                      const float* __restrict__ X, float* __restrict__ out) {
    int b = blockIdx.x >> 4;
    int qc = blockIdx.x & 15;
    int t = threadIdx.x;
    int q = t & 63, ks = t >> 6;
    __shared__ float kx[1024][3];
    __shared__ __align__(16) float xv[1024][8];
    __shared__ float red[4][64][8];
    for (int i = t; i < 3072; i += 256) kx[i / 3][i % 3] = Ks[b * 3072 + i];
    for (int i = t; i < 8192; i += 256) xv[i >> 3][i & 7] = X[b * 8192 + i];
    __syncthreads();
    int gq = b * 1024 + qc * 64 + q;
    const float* qp = Qs + (long)gq * 3;
    float qx = qp[0], qy = qp[1], qz = qp[2];
    float acc[8] = {};
    int k0 = ks * 256;
#pragma unroll 2
    for (int k = k0; k < k0 + 256; k++) {
        float dx = qx - kx[k][0], dy = qy - kx[k][1], dz = qz - kx[k][2];
        float w = __expf(-sqrtf(dx * dx + dy * dy + dz * dz + 1e-12f));
        float4 xa = *(const float4*)&xv[k][0];
        float4 xb = *(const float4*)&xv[k][4];
        acc[0] += w * xa.x; acc[1] += w * xa.y; acc[2] += w * xa.z; acc[3] += w * xa.w;
        acc[4] += w * xb.x; acc[5] += w * xb.y; acc[6] += w * xb.z; acc[7] += w * xb.w;
    }
#pragma unroll
    for (int c = 0; c < 8; c++) red[ks][q][c] = acc[c];
    __syncthreads();
    if (ks == 0) {
        float* op = out + (long)gq * 8;
#pragma unroll
        for (int c = 0; c < 8; c++)
            op[c] = red[0][q][c] + red[1][q][c] + red[2][q][c] + red[3][q][c];
    }
}

extern "C" void kernel_launch(void* const* d_in, const int* in_sizes, int n_in,
                              void* d_out, int out_size, void* d_ws, size_t ws_size,
                              hipStream_t stream) {
    const float* KEY   = (const float*)d_in[0];
    const float* VALUE = (const float*)d_in[1];
    const float* QUERY = (const float*)d_in[2];
    const float* W1w = (const float*)d_in[3];  const float* W1b = (const float*)d_in[4];
    const float* W2w = (const float*)d_in[5];  const float* W2b = (const float*)d_in[6];
    const float* W3w = (const float*)d_in[7];  const float* W3b = (const float*)d_in[8];
    const float* Wv1w = (const float*)d_in[9]; const float* Wv1b = (const float*)d_in[10];
    const float* Wv2w = (const float*)d_in[11];const float* Wv2b = (const float*)d_in[12];
    const float* Wv3w = (const float*)d_in[13];const float* Wv3b = (const float*)d_in[14];

    float* ws  = (float*)d_ws;
    float* C    = ws;                 // 16*1024*1024
    float* Ks   = C + 16777216;       // 16*1024*3
    float* Qs   = Ks + 49152;
    float* Vs   = Qs + 49152;         // 16*1024*8 (becomes X in place)
    float* W2T  = Vs + 131072;
    float* Wv2T = W2T + 16384;
    float* invd = Wv2T + 16384;       // 16*1024

    float* out = (float*)d_out;

    hipLaunchKernelGGL(k_transpose, dim3(128), dim3(256), 0, stream, W2w, Wv2w, W2T, Wv2T);
    hipLaunchKernelGGL((k_mlp<3, 32>), dim3(512), dim3(128), 0, stream,
                       KEY, W1w, W1b, W2T, W2b, W3w, W3b, Ks);
    hipLaunchKernelGGL((k_mlp<3, 32>), dim3(512), dim3(128), 0, stream,
                       QUERY, W1w, W1b, W2T, W2b, W3w, W3b, Qs);
    hipLaunchKernelGGL((k_mlp<8, 16>), dim3(1024), dim3(128), 0, stream,
                       VALUE, Wv1w, Wv1b, Wv2T, Wv2b, Wv3w, Wv3b, Vs);
    hipLaunchKernelGGL(k_buildC, dim3(65536), dim3(256), 0, stream, Ks, C);

    for (int s = 0; s < 8; s++) {
        int o = s * 128;
        hipLaunchKernelGGL(k_potf, dim3(16), dim3(256), 0, stream, C, invd, o);
        int m = 1024 - o - 128;
        if (m > 0) {
            hipLaunchKernelGGL(k_trsm, dim3(m / 64, 16), dim3(64), 0, stream, C, invd, o);
            int nt = m / 128;
            int np = nt * (nt + 1) / 2;
            hipLaunchKernelGGL(k_syrk, dim3(np, 16), dim3(256), 0, stream, C, o);
        }
    }
    hipLaunchKernelGGL(k_solve, dim3(16), dim3(1024), 0, stream, C, invd, Vs);
    hipLaunchKernelGGL(k_out, dim3(256), dim3(256), 0, stream, Qs, Ks, Vs, out);
}